// Round 10
// baseline (199.927 us; speedup 1.0000x reference)
//
#include <hip/hip_runtime.h>

typedef unsigned short u16;
typedef __attribute__((ext_vector_type(8))) short bf16x8;   // MFMA A/B frag (8 bf16)
typedef __attribute__((ext_vector_type(8))) unsigned short u16x8;
typedef __attribute__((ext_vector_type(4))) float f32x4;    // MFMA C/D frag

#define MFMA16(a, b, c) __builtin_amdgcn_mfma_f32_16x16x32_bf16((a), (b), (c), 0, 0, 0)

// async global->LDS, 16B per lane; LDS dest = wave-uniform base + lane*16
__device__ __forceinline__ void gll16(const void* g, void* l) {
    __builtin_amdgcn_global_load_lds(
        (const __attribute__((address_space(1))) unsigned int*)g,
        (__attribute__((address_space(3))) unsigned int*)l, 16, 0, 0);
}

__device__ __forceinline__ u16 f2b(float f) {   // f32 -> bf16 RNE (scalar)
    unsigned int u = __float_as_uint(f);
    u += 0x7fffu + ((u >> 16) & 1u);
    return (u16)(u >> 16);
}

__device__ __forceinline__ unsigned int pkbf(float a, float b) {  // packed bf16x2
    return (unsigned int)f2b(a) | ((unsigned int)f2b(b) << 16);
}

// ---------------------------------------------------------------- one cast kernel
// blocks 0..2047: x (4M f32). blocks 2048..4095: the four 1M-element weights.
__global__ __launch_bounds__(256) void cast_all(const float* __restrict__ x,
                                                const float* __restrict__ w0,
                                                const float* __restrict__ w1,
                                                const float* __restrict__ w2,
                                                const float* __restrict__ w3,
                                                u16* __restrict__ xb,
                                                u16* __restrict__ wb) {
    const int bid = blockIdx.x;
    const float* s; u16* d; int off;
    if (bid < 2048) { s = x; d = xb; off = bid; }
    else {
        const int wi = (bid - 2048) >> 9;
        s = (wi == 0) ? w0 : (wi == 1) ? w1 : (wi == 2) ? w2 : w3;
        d = wb + (size_t)wi * 1048576;
        off = (bid - 2048) & 511;
    }
    const int i = (off * 256 + threadIdx.x) * 8;
    float4 a = *(const float4*)(s + i);
    float4 b = *(const float4*)(s + i + 4);
    *(uint4*)(d + i) = make_uint4(pkbf(a.x, a.y), pkbf(a.z, a.w),
                                  pkbf(b.x, b.y), pkbf(b.z, b.w));
}

// ---------------------------------------------------------------- GEMM, dbuf K-loop
// Y = A[M,K] @ W[rows,K]^T, bf16 in, fp32 acc, BMxBN tile, BK=32, 4 waves (2x2),
// LDS double-buffered: ONE barrier per iter, prefetch for k+1 issued right after
// the barrier so its latency is hidden behind this iter's compute.
// MODE 0: f32 out, stride ldY. MODE 1 (BM=BN=128): fused QKV epilogue — cols<2048
// -> bf16 qk (stride 2048); cols>=2048 (V proj) -> transposed into vT.
template <int BM, int BN, int MODE>
__global__ __launch_bounds__(256) void gemm_bt(const u16* __restrict__ A,
                                               const u16* __restrict__ W,
                                               void* __restrict__ Yv,
                                               u16* __restrict__ vT,
                                               int K, int ldY) {
    constexpr int MI = BM / 32, NJ = BN / 32;      // frags per wave
    constexpr int ACH = BM / 16;                   // A staging chunks (1KB each)
    constexpr int NPW = (BM + BN) / 64;            // chunks per wave
    __shared__ u16 As[2][BM * 32];
    __shared__ u16 Bs[2][BN * 32];
    const int t = threadIdx.x, w = t >> 6, lane = t & 63;
    const int quad = lane >> 4, m16 = lane & 15;
    const int wr = (w >> 1) * (BM / 2), wc = (w & 1) * (BN / 2);
    const int row0 = blockIdx.x * BM, col0 = blockIdx.y * BN;
    const int srow = lane >> 2, scol = (lane & 3) * 8;

    auto stage = [&](int buf, int k0) {
#pragma unroll
        for (int cc = 0; cc < NPW; ++cc) {
            const int c = w * NPW + cc;
            if (c < ACH)
                gll16(A + (size_t)(row0 + c * 16 + srow) * K + k0 + scol,
                      &As[buf][c * 512]);
            else
                gll16(W + (size_t)(col0 + (c - ACH) * 16 + srow) * K + k0 + scol,
                      &Bs[buf][(c - ACH) * 512]);
        }
    };

    f32x4 acc[MI][NJ];
#pragma unroll
    for (int i = 0; i < MI; ++i)
#pragma unroll
        for (int j = 0; j < NJ; ++j) acc[i][j] = (f32x4){0.f, 0.f, 0.f, 0.f};

    stage(0, 0);
    for (int k0 = 0; k0 < K; k0 += 32) {
        const int buf = (k0 >> 5) & 1;
        __syncthreads();                       // tile k0 landed; buf^1 free
        if (k0 + 32 < K) stage(buf ^ 1, k0 + 32);   // hidden behind compute
        bf16x8 af[MI], bf[NJ];
#pragma unroll
        for (int i = 0; i < MI; ++i)
            af[i] = *(const bf16x8*)&As[buf][(wr + i * 16 + m16) * 32 + quad * 8];
#pragma unroll
        for (int j = 0; j < NJ; ++j)
            bf[j] = *(const bf16x8*)&Bs[buf][(wc + j * 16 + m16) * 32 + quad * 8];
#pragma unroll
        for (int i = 0; i < MI; ++i)
#pragma unroll
            for (int j = 0; j < NJ; ++j) acc[i][j] = MFMA16(af[i], bf[j], acc[i][j]);
    }
    // epilogue: D[row=quad*4+r][col=m16] per 16x16 tile
    if constexpr (MODE == 0) {
#pragma unroll
        for (int i = 0; i < MI; ++i)
#pragma unroll
            for (int j = 0; j < NJ; ++j)
#pragma unroll
                for (int r = 0; r < 4; ++r)
                    ((float*)Yv)[(size_t)(row0 + wr + i * 16 + quad * 4 + r) * ldY +
                                 col0 + wc + j * 16 + m16] = acc[i][j][r];
    } else {
        if (col0 < 2048) {              // Q/K projection -> bf16, stride 2048
            u16* qk = (u16*)Yv;
#pragma unroll
            for (int i = 0; i < MI; ++i)
#pragma unroll
                for (int j = 0; j < NJ; ++j)
#pragma unroll
                    for (int r = 0; r < 4; ++r)
                        qk[(size_t)(row0 + wr + i * 16 + quad * 4 + r) * 2048 +
                           col0 + wc + j * 16 + m16] = f2b(acc[i][j][r]);
        } else {                        // V projection -> transposed vT
#pragma unroll
            for (int i = 0; i < MI; ++i) {
                const int rbase = row0 + wr + i * 16;
                const int bb = rbase >> 10;
                const int tok0 = (rbase & 1023) + quad * 4;
#pragma unroll
                for (int j = 0; j < NJ; ++j) {
                    const int vTrow = bb * 1024 + (col0 + wc + j * 16 + m16 - 2048);
                    *(uint2*)(vT + (size_t)vTrow * 1024 + tok0) =
                        make_uint2(pkbf(acc[i][j][0], acc[i][j][1]),
                                   pkbf(acc[i][j][2], acc[i][j][3]));
                }
            }
        }
    }
}

// ---------------------------------------------------------------- based attention
// BARRIER-FREE K-loop. Triangular pairing (tA=p, tB=15-p: 17 units/block).
// K/V fragment lane-layouts are wave-invariant -> each wave loads its frags
// DIRECTLY global->registers (per-lane 16B), ping-pong double-buffered one
// tile ahead; intra-block 4x redundancy absorbed by L1/L2. Q in registers.
// Only LDS use: the Ss C-layout->A-layout round-trip, wave-private rows
// (lgkmcnt-ordered by compiler; no __syncthreads anywhere).
struct KVFrags { bf16x8 k[2][4]; bf16x8 v[2][4]; };

__global__ __launch_bounds__(256, 2) void based_attn(const u16* __restrict__ qkm,
                                                     const u16* __restrict__ vT,
                                                     u16* __restrict__ o) {
    __shared__ u16 SsA[2][64][32];      // [kb][qrow][32 keys] (wave-private rows)
    __shared__ u16 SsB[2][64][32];

    const int t = threadIdx.x, w = t >> 6, lane = t & 63;
    const int quad = lane >> 4, m16 = lane & 15;
    const int p = blockIdx.x, h = blockIdx.y, b = blockIdx.z;
    const int tA = p, tB = 15 - p;
    const int qrow = w * 16 + m16;       // this lane's q-row (local to tile)

    const size_t qbase = (size_t)b * 1024 * 2048 + h * 64;   // + row*2048
    const size_t kbase = qbase + 1024;
    const size_t vbase = ((size_t)b * 1024 + h * 64) * 1024; // + vd*1024 + tok

    // Q frags in registers (4 per-lane 16B loads, once)
    bf16x8 qfA[2], qfB[2];
#pragma unroll
    for (int kd = 0; kd < 2; ++kd) {
        qfA[kd] = *(const bf16x8*)(qkm + qbase +
                   (size_t)(tA * 64 + qrow) * 2048 + kd * 32 + quad * 8);
        qfB[kd] = *(const bf16x8*)(qkm + qbase +
                   (size_t)(tB * 64 + qrow) * 2048 + kd * 32 + quad * 8);
    }

    bf16x8 ones;
#pragma unroll
    for (int e = 0; e < 8; ++e) ones[e] = (short)0x3F80;

    f32x4 numA[4], numB[4], denA, denB;
    denA = denB = (f32x4){0.f, 0.f, 0.f, 0.f};
#pragma unroll
    for (int j = 0; j < 4; ++j) numA[j] = numB[j] = (f32x4){0.f, 0.f, 0.f, 0.f};

    auto load_tile = [&](int kt, KVFrags& F) {
#pragma unroll
        for (int kd = 0; kd < 2; ++kd)
#pragma unroll
            for (int jk = 0; jk < 4; ++jk)
                F.k[kd][jk] = *(const bf16x8*)(qkm + kbase +
                    (size_t)(kt * 64 + jk * 16 + m16) * 2048 + kd * 32 + quad * 8);
#pragma unroll
        for (int kb = 0; kb < 2; ++kb)
#pragma unroll
            for (int j = 0; j < 4; ++j)
                F.v[kb][j] = *(const bf16x8*)(vT + vbase +
                    (size_t)(j * 16 + m16) * 1024 + kt * 64 + kb * 32 + quad * 8);
    };

    auto compute = [&](const KVFrags& F, int kt) {
        const bool doA = (kt <= tA);
        // Phase 1: S^T = K * Q^T (shared K-frags for both units)
        f32x4 sA[4], sB[4];
#pragma unroll
        for (int jk = 0; jk < 4; ++jk)
            sA[jk] = sB[jk] = (f32x4){0.f, 0.f, 0.f, 0.f};
#pragma unroll
        for (int kd = 0; kd < 2; ++kd)
#pragma unroll
            for (int jk = 0; jk < 4; ++jk) {
                sB[jk] = MFMA16(F.k[kd][jk], qfB[kd], sB[jk]);
                if (doA) sA[jk] = MFMA16(F.k[kd][jk], qfA[kd], sA[jk]);
            }
        // transform: sc = 0.5*(s+1)^2 + 0.5, s = dot/8; mask on diagonal tiles
#pragma unroll
        for (int jk = 0; jk < 4; ++jk) {
            const int kl = jk * 16 + quad * 4;
            float scB[4];
#pragma unroll
            for (int r = 0; r < 4; ++r) {
                const float u = fmaf(sB[jk][r], 0.125f, 1.0f);
                scB[r] = fmaf(u * 0.5f, u, 0.5f);
            }
            if (kt == tB) {
#pragma unroll
                for (int r = 0; r < 4; ++r)
                    if (kl + r > qrow) scB[r] = 0.f;
            }
            *(uint2*)&SsB[kl >> 5][qrow][kl & 31] =
                make_uint2(pkbf(scB[0], scB[1]), pkbf(scB[2], scB[3]));
            if (doA) {
                float scA[4];
#pragma unroll
                for (int r = 0; r < 4; ++r) {
                    const float u = fmaf(sA[jk][r], 0.125f, 1.0f);
                    scA[r] = fmaf(u * 0.5f, u, 0.5f);
                }
                if (kt == tA) {
#pragma unroll
                    for (int r = 0; r < 4; ++r)
                        if (kl + r > qrow) scA[r] = 0.f;
                }
                *(uint2*)&SsA[kl >> 5][qrow][kl & 31] =
                    make_uint2(pkbf(scA[0], scA[1]), pkbf(scA[2], scA[3]));
            }
        }
        // Phase 2: num += S*V, den += S*ones (shared V-frags); same-wave LDS
        // round-trip ordered by lgkmcnt — no barrier.
#pragma unroll
        for (int kb = 0; kb < 2; ++kb) {
            bf16x8 sfB = *(const bf16x8*)&SsB[kb][qrow][quad * 8];
#pragma unroll
            for (int j = 0; j < 4; ++j) numB[j] = MFMA16(sfB, F.v[kb][j], numB[j]);
            denB = MFMA16(sfB, ones, denB);
            if (doA) {
                bf16x8 sfA = *(const bf16x8*)&SsA[kb][qrow][quad * 8];
#pragma unroll
                for (int j = 0; j < 4; ++j) numA[j] = MFMA16(sfA, F.v[kb][j], numA[j]);
                denA = MFMA16(sfA, ones, denA);
            }
        }
    };

    // ping-pong register double-buffer: loads for kt+1 issued before compute kt
    KVFrags F0, F1;
    load_tile(0, F0);
    int kt = 0;
    while (true) {
        if (kt < tB) load_tile(kt + 1, F1);
        compute(F0, kt);
        if (++kt > tB) break;
        if (kt < tB) load_tile(kt + 1, F0);
        compute(F1, kt);
        if (++kt > tB) break;
    }

    // epilogue: o[token][h*64+vdim] = num/den (bf16)
#pragma unroll
    for (int r = 0; r < 4; ++r) {
        const float invA = 1.0f / denA[r], invB = 1.0f / denB[r];
        const int rowoff = w * 16 + quad * 4 + r;
        const size_t tokA = (size_t)(b * 1024 + tA * 64 + rowoff);
        const size_t tokB = (size_t)(b * 1024 + tB * 64 + rowoff);
#pragma unroll
        for (int j = 0; j < 4; ++j) {
            o[tokA * 1024 + h * 64 + j * 16 + m16] = f2b(numA[j][r] * invA);
            o[tokB * 1024 + h * 64 + j * 16 + m16] = f2b(numB[j][r] * invB);
        }
    }
}

// ---------------------------------------------------------------- launch
extern "C" void kernel_launch(void* const* d_in, const int* in_sizes, int n_in,
                              void* d_out, int out_size, void* d_ws, size_t ws_size,
                              hipStream_t stream) {
    const float* x  = (const float*)d_in[0];
    const float* Wq = (const float*)d_in[1];
    const float* Wk = (const float*)d_in[2];
    const float* Wv = (const float*)d_in[3];
    const float* Wo = (const float*)d_in[4];
    float* out = (float*)d_out;

    const size_t MEL = 4096ull * 1024ull;        // 4M elements
    u16* xb   = (u16*)d_ws;                      // 4096 x 1024
    u16* Wqkv = xb + MEL;                        // 3072 x 1024 (Wq|Wk|Wv rows)
    u16* Wob  = Wqkv + 3ull * 1024 * 1024;       // 1024 x 1024 (contiguous after)
    u16* qk   = Wob + 1024ull * 1024;            // 4096 x 2048 (q|k)
    u16* vT   = qk + 2ull * MEL;                 // [b*1024+h*64+vd][1024 tokens]
    u16* o    = vT + MEL;                        // 4096 x 1024

    cast_all<<<4096, 256, 0, stream>>>(x, Wq, Wk, Wv, Wo, xb, Wqkv);

    dim3 gq(32, 24);   // 4096/128 x 3072/128; y>=16 blocks write vT directly
    gemm_bt<128, 128, 1><<<gq, 256, 0, stream>>>(xb, Wqkv, qk, vT, 1024, 2048);

    dim3 ga(8, 16, 4); // pair index x heads x batch — uniform work per block
    based_attn<<<ga, 256, 0, stream>>>(qk, vT, o);

    dim3 go(64, 16);   // 64x64 tiles -> 1024 blocks, 4/CU, dbuf 16KB LDS
    gemm_bt<64, 64, 0><<<go, 256, 0, stream>>>(o, Wob, (void*)out, nullptr, 1024, 1024);
}

// Round 11
// 164.764 us; speedup vs baseline: 1.2134x; 1.2134x over previous
//
#include <hip/hip_runtime.h>

typedef unsigned short u16;
typedef __attribute__((ext_vector_type(8))) short bf16x8;   // MFMA A/B frag (8 bf16)
typedef __attribute__((ext_vector_type(8))) unsigned short u16x8;
typedef __attribute__((ext_vector_type(4))) float f32x4;    // MFMA C/D frag

#define MFMA16(a, b, c) __builtin_amdgcn_mfma_f32_16x16x32_bf16((a), (b), (c), 0, 0, 0)

// async global->LDS, 16B per lane; LDS dest = wave-uniform base + lane*16
__device__ __forceinline__ void gll16(const void* g, void* l) {
    __builtin_amdgcn_global_load_lds(
        (const __attribute__((address_space(1))) unsigned int*)g,
        (__attribute__((address_space(3))) unsigned int*)l, 16, 0, 0);
}

__device__ __forceinline__ u16 f2b(float f) {   // f32 -> bf16 RNE (scalar)
    unsigned int u = __float_as_uint(f);
    u += 0x7fffu + ((u >> 16) & 1u);
    return (u16)(u >> 16);
}

__device__ __forceinline__ unsigned int pkbf(float a, float b) {  // packed bf16x2
    return (unsigned int)f2b(a) | ((unsigned int)f2b(b) << 16);
}

// ---------------------------------------------------------------- one cast kernel
// blocks 0..2047: x (4M f32). blocks 2048..4095: the four 1M-element weights.
__global__ __launch_bounds__(256) void cast_all(const float* __restrict__ x,
                                                const float* __restrict__ w0,
                                                const float* __restrict__ w1,
                                                const float* __restrict__ w2,
                                                const float* __restrict__ w3,
                                                u16* __restrict__ xb,
                                                u16* __restrict__ wb) {
    const int bid = blockIdx.x;
    const float* s; u16* d; int off;
    if (bid < 2048) { s = x; d = xb; off = bid; }
    else {
        const int wi = (bid - 2048) >> 9;
        s = (wi == 0) ? w0 : (wi == 1) ? w1 : (wi == 2) ? w2 : w3;
        d = wb + (size_t)wi * 1048576;
        off = (bid - 2048) & 511;
    }
    const int i = (off * 256 + threadIdx.x) * 8;
    float4 a = *(const float4*)(s + i);
    float4 b = *(const float4*)(s + i + 4);
    *(uint4*)(d + i) = make_uint4(pkbf(a.x, a.y), pkbf(a.z, a.w),
                                  pkbf(b.x, b.y), pkbf(b.z, b.w));
}

// ---------------------------------------------------------------- GEMM, dbuf K-loop
// Y = A[M,K] @ W[rows,K]^T, bf16 in, fp32 acc, BMxBN tile, BK=32, 4 waves (2x2),
// LDS double-buffered: ONE barrier per iter, prefetch for k+1 issued right after
// the barrier so its latency is hidden behind this iter's compute.
// MODE 0: f32 out, stride ldY. MODE 1 (BM=BN=128): fused QKV epilogue — cols<2048
// -> bf16 qk (stride 2048); cols>=2048 (V proj) -> transposed into vT.
template <int BM, int BN, int MODE>
__global__ __launch_bounds__(256) void gemm_bt(const u16* __restrict__ A,
                                               const u16* __restrict__ W,
                                               void* __restrict__ Yv,
                                               u16* __restrict__ vT,
                                               int K, int ldY) {
    constexpr int MI = BM / 32, NJ = BN / 32;      // frags per wave
    constexpr int ACH = BM / 16;                   // A staging chunks (1KB each)
    constexpr int NPW = (BM + BN) / 64;            // chunks per wave
    __shared__ u16 As[2][BM * 32];
    __shared__ u16 Bs[2][BN * 32];
    const int t = threadIdx.x, w = t >> 6, lane = t & 63;
    const int quad = lane >> 4, m16 = lane & 15;
    const int wr = (w >> 1) * (BM / 2), wc = (w & 1) * (BN / 2);
    const int row0 = blockIdx.x * BM, col0 = blockIdx.y * BN;
    const int srow = lane >> 2, scol = (lane & 3) * 8;

    auto stage = [&](int buf, int k0) {
#pragma unroll
        for (int cc = 0; cc < NPW; ++cc) {
            const int c = w * NPW + cc;
            if (c < ACH)
                gll16(A + (size_t)(row0 + c * 16 + srow) * K + k0 + scol,
                      &As[buf][c * 512]);
            else
                gll16(W + (size_t)(col0 + (c - ACH) * 16 + srow) * K + k0 + scol,
                      &Bs[buf][(c - ACH) * 512]);
        }
    };

    f32x4 acc[MI][NJ];
#pragma unroll
    for (int i = 0; i < MI; ++i)
#pragma unroll
        for (int j = 0; j < NJ; ++j) acc[i][j] = (f32x4){0.f, 0.f, 0.f, 0.f};

    stage(0, 0);
    for (int k0 = 0; k0 < K; k0 += 32) {
        const int buf = (k0 >> 5) & 1;
        __syncthreads();                       // tile k0 landed; buf^1 free
        if (k0 + 32 < K) stage(buf ^ 1, k0 + 32);   // hidden behind compute
        bf16x8 af[MI], bf[NJ];
#pragma unroll
        for (int i = 0; i < MI; ++i)
            af[i] = *(const bf16x8*)&As[buf][(wr + i * 16 + m16) * 32 + quad * 8];
#pragma unroll
        for (int j = 0; j < NJ; ++j)
            bf[j] = *(const bf16x8*)&Bs[buf][(wc + j * 16 + m16) * 32 + quad * 8];
#pragma unroll
        for (int i = 0; i < MI; ++i)
#pragma unroll
            for (int j = 0; j < NJ; ++j) acc[i][j] = MFMA16(af[i], bf[j], acc[i][j]);
    }
    // epilogue: D[row=quad*4+r][col=m16] per 16x16 tile
    if constexpr (MODE == 0) {
#pragma unroll
        for (int i = 0; i < MI; ++i)
#pragma unroll
            for (int j = 0; j < NJ; ++j)
#pragma unroll
                for (int r = 0; r < 4; ++r)
                    ((float*)Yv)[(size_t)(row0 + wr + i * 16 + quad * 4 + r) * ldY +
                                 col0 + wc + j * 16 + m16] = acc[i][j][r];
    } else {
        if (col0 < 2048) {              // Q/K projection -> bf16, stride 2048
            u16* qk = (u16*)Yv;
#pragma unroll
            for (int i = 0; i < MI; ++i)
#pragma unroll
                for (int j = 0; j < NJ; ++j)
#pragma unroll
                    for (int r = 0; r < 4; ++r)
                        qk[(size_t)(row0 + wr + i * 16 + quad * 4 + r) * 2048 +
                           col0 + wc + j * 16 + m16] = f2b(acc[i][j][r]);
        } else {                        // V projection -> transposed vT
#pragma unroll
            for (int i = 0; i < MI; ++i) {
                const int rbase = row0 + wr + i * 16;
                const int bb = rbase >> 10;
                const int tok0 = (rbase & 1023) + quad * 4;
#pragma unroll
                for (int j = 0; j < NJ; ++j) {
                    const int vTrow = bb * 1024 + (col0 + wc + j * 16 + m16 - 2048);
                    *(uint2*)(vT + (size_t)vTrow * 1024 + tok0) =
                        make_uint2(pkbf(acc[i][j][0], acc[i][j][1]),
                                   pkbf(acc[i][j][2], acc[i][j][3]));
                }
            }
        }
    }
}

// ---------------------------------------------------------------- based attention
// Triangular pairing (tA=p, tB=15-p: 17 units/block, uniform). LDS-staged k/v
// (coalesced gll16 — R10 showed per-lane global frag loads regress), Q in
// registers. TWO kt-tiles per barrier: stage 32 KB/group, double-buffered, one
// __syncthreads per group -> half the barriers, 2x compute per drain.
// A/B units computed jointly sharing k/v frags; separate wave-private Ss.
__global__ __launch_bounds__(256) void based_attn(const u16* __restrict__ qkm,
                                                  const u16* __restrict__ vT,
                                                  u16* __restrict__ o) {
    __shared__ u16 ks[2][2][2][64][32];  // [buf][slot][dblk][key][32]
    __shared__ u16 vs[2][2][2][64][32];  // [buf][slot][kb][vdim][32 keys]
    __shared__ u16 SsA[2][64][32];       // [kb][qrow][32 keys] (wave-private rows)
    __shared__ u16 SsB[2][64][32];

    const int t = threadIdx.x, w = t >> 6, lane = t & 63;
    const int quad = lane >> 4, m16 = lane & 15;
    const int p = blockIdx.x, h = blockIdx.y, b = blockIdx.z;
    const int tA = p, tB = 15 - p;
    const int srow = lane >> 2, s8 = (lane & 3) * 8;
    const int qrow = w * 16 + m16;       // this lane's q-row (local to tile)

    const size_t qbase = (size_t)b * 1024 * 2048 + h * 64;   // + row*2048
    const size_t kbase = qbase + 1024;
    const size_t vbase = ((size_t)b * 1024 + h * 64) * 1024; // + vd*1024 + tok

    // Q frags in registers (4 scattered 16B loads, once — outside the loop)
    bf16x8 qfA[2], qfB[2];
#pragma unroll
    for (int kd = 0; kd < 2; ++kd) {
        qfA[kd] = *(const bf16x8*)(qkm + qbase +
                   (size_t)(tA * 64 + qrow) * 2048 + kd * 32 + quad * 8);
        qfB[kd] = *(const bf16x8*)(qkm + qbase +
                   (size_t)(tB * 64 + qrow) * 2048 + kd * 32 + quad * 8);
    }

    // stage one kt-tile into [buf][slot]; wave w takes chunks 2w, 2w+1 (k and v)
    auto stage_tile = [&](int kt, int buf, int slot) {
#pragma unroll
        for (int cc = 0; cc < 2; ++cc) {
            const int c = w * 2 + cc;
            const int blk = c >> 2, rc = c & 3;
            gll16(qkm + kbase + (size_t)(kt * 64 + rc * 16 + srow) * 2048 + blk * 32 + s8,
                  &ks[buf][slot][blk][rc * 16][0]);
            gll16(vT + vbase + (size_t)(rc * 16 + srow) * 1024 + kt * 64 + blk * 32 + s8,
                  &vs[buf][slot][blk][rc * 16][0]);
        }
    };

    bf16x8 ones;
#pragma unroll
    for (int e = 0; e < 8; ++e) ones[e] = (short)0x3F80;

    f32x4 numA[4], numB[4], denA, denB;
    denA = denB = (f32x4){0.f, 0.f, 0.f, 0.f};
#pragma unroll
    for (int j = 0; j < 4; ++j) numA[j] = numB[j] = (f32x4){0.f, 0.f, 0.f, 0.f};

    auto compute = [&](int buf, int slot, int kt) {
        const bool doA = (kt <= tA);
        // Phase 1: S^T = K * Q^T (shared K-frags for both units)
        f32x4 sA[4], sB[4];
#pragma unroll
        for (int jk = 0; jk < 4; ++jk)
            sA[jk] = sB[jk] = (f32x4){0.f, 0.f, 0.f, 0.f};
#pragma unroll
        for (int kd = 0; kd < 2; ++kd)
#pragma unroll
            for (int jk = 0; jk < 4; ++jk) {
                bf16x8 af = *(const bf16x8*)&ks[buf][slot][kd][jk * 16 + m16][quad * 8];
                sB[jk] = MFMA16(af, qfB[kd], sB[jk]);
                if (doA) sA[jk] = MFMA16(af, qfA[kd], sA[jk]);
            }
        // transform: sc = 0.5*(s+1)^2 + 0.5, s = dot/8; mask on diagonal tiles
#pragma unroll
        for (int jk = 0; jk < 4; ++jk) {
            const int kl = jk * 16 + quad * 4;
            float scB[4];
#pragma unroll
            for (int r = 0; r < 4; ++r) {
                const float u = fmaf(sB[jk][r], 0.125f, 1.0f);
                scB[r] = fmaf(u * 0.5f, u, 0.5f);
            }
            if (kt == tB) {
#pragma unroll
                for (int r = 0; r < 4; ++r)
                    if (kl + r > qrow) scB[r] = 0.f;
            }
            *(uint2*)&SsB[kl >> 5][qrow][kl & 31] =
                make_uint2(pkbf(scB[0], scB[1]), pkbf(scB[2], scB[3]));
            if (doA) {
                float scA[4];
#pragma unroll
                for (int r = 0; r < 4; ++r) {
                    const float u = fmaf(sA[jk][r], 0.125f, 1.0f);
                    scA[r] = fmaf(u * 0.5f, u, 0.5f);
                }
                if (kt == tA) {
#pragma unroll
                    for (int r = 0; r < 4; ++r)
                        if (kl + r > qrow) scA[r] = 0.f;
                }
                *(uint2*)&SsA[kl >> 5][qrow][kl & 31] =
                    make_uint2(pkbf(scA[0], scA[1]), pkbf(scA[2], scA[3]));
            }
        }
        // Phase 2: num += S*V, den += S*ones (shared V-frags); same-wave LDS
        // round-trip ordered by lgkmcnt — no barrier needed.
#pragma unroll
        for (int kb = 0; kb < 2; ++kb) {
            bf16x8 vf[4];
#pragma unroll
            for (int j = 0; j < 4; ++j)
                vf[j] = *(const bf16x8*)&vs[buf][slot][kb][j * 16 + m16][quad * 8];
            bf16x8 sfB = *(const bf16x8*)&SsB[kb][qrow][quad * 8];
#pragma unroll
            for (int j = 0; j < 4; ++j) numB[j] = MFMA16(sfB, vf[j], numB[j]);
            denB = MFMA16(sfB, ones, denB);
            if (doA) {
                bf16x8 sfA = *(const bf16x8*)&SsA[kb][qrow][quad * 8];
#pragma unroll
                for (int j = 0; j < 4; ++j) numA[j] = MFMA16(sfA, vf[j], numA[j]);
                denA = MFMA16(sfA, ones, denA);
            }
        }
    };

    // prologue: group 0 = tiles 0,1 (tB >= 8, so tile 1 always exists)
    stage_tile(0, 0, 0);
    stage_tile(1, 0, 1);

    const int ngroups = (tB + 2) >> 1;   // tiles 0..tB in groups of 2
    for (int g = 0; g < ngroups; ++g) {
        const int buf = g & 1;
        __syncthreads();                 // group g landed; buf^1 free to refill
        const int kn = (g + 1) * 2;      // prefetch group g+1 (hidden by compute)
        if (kn <= tB) {
            stage_tile(kn, buf ^ 1, 0);
            if (kn + 1 <= tB) stage_tile(kn + 1, buf ^ 1, 1);
        }
        const int kt0 = g * 2;
        compute(buf, 0, kt0);
        if (kt0 + 1 <= tB) compute(buf, 1, kt0 + 1);
    }

    // epilogue: o[token][h*64+vdim] = num/den (bf16)
#pragma unroll
    for (int r = 0; r < 4; ++r) {
        const float invA = 1.0f / denA[r], invB = 1.0f / denB[r];
        const int rowoff = w * 16 + quad * 4 + r;
        const size_t tokA = (size_t)(b * 1024 + tA * 64 + rowoff);
        const size_t tokB = (size_t)(b * 1024 + tB * 64 + rowoff);
#pragma unroll
        for (int j = 0; j < 4; ++j) {
            o[tokA * 1024 + h * 64 + j * 16 + m16] = f2b(numA[j][r] * invA);
            o[tokB * 1024 + h * 64 + j * 16 + m16] = f2b(numB[j][r] * invB);
        }
    }
}

// ---------------------------------------------------------------- launch
extern "C" void kernel_launch(void* const* d_in, const int* in_sizes, int n_in,
                              void* d_out, int out_size, void* d_ws, size_t ws_size,
                              hipStream_t stream) {
    const float* x  = (const float*)d_in[0];
    const float* Wq = (const float*)d_in[1];
    const float* Wk = (const float*)d_in[2];
    const float* Wv = (const float*)d_in[3];
    const float* Wo = (const float*)d_in[4];
    float* out = (float*)d_out;

    const size_t MEL = 4096ull * 1024ull;        // 4M elements
    u16* xb   = (u16*)d_ws;                      // 4096 x 1024
    u16* Wqkv = xb + MEL;                        // 3072 x 1024 (Wq|Wk|Wv rows)
    u16* Wob  = Wqkv + 3ull * 1024 * 1024;       // 1024 x 1024 (contiguous after)
    u16* qk   = Wob + 1024ull * 1024;            // 4096 x 2048 (q|k)
    u16* vT   = qk + 2ull * MEL;                 // [b*1024+h*64+vd][1024 tokens]
    u16* o    = vT + MEL;                        // 4096 x 1024

    cast_all<<<4096, 256, 0, stream>>>(x, Wq, Wk, Wv, Wo, xb, Wqkv);

    dim3 gq(32, 24);   // 4096/128 x 3072/128; y>=16 blocks write vT directly
    gemm_bt<128, 128, 1><<<gq, 256, 0, stream>>>(xb, Wqkv, qk, vT, 1024, 2048);

    dim3 ga(8, 16, 4); // pair index x heads x batch — uniform work per block
    based_attn<<<ga, 256, 0, stream>>>(qk, vT, o);

    dim3 go(64, 16);   // 64x64 tiles -> 1024 blocks, 4/CU, dbuf 16KB LDS
    gemm_bt<64, 64, 0><<<go, 256, 0, stream>>>(o, Wob, (void*)out, nullptr, 1024, 1024);
}

// Round 12
// 161.314 us; speedup vs baseline: 1.2394x; 1.0214x over previous
//
#include <hip/hip_runtime.h>

typedef unsigned short u16;
typedef __attribute__((ext_vector_type(8))) short bf16x8;   // MFMA A/B frag (8 bf16)
typedef __attribute__((ext_vector_type(8))) unsigned short u16x8;
typedef __attribute__((ext_vector_type(4))) float f32x4;    // MFMA C/D frag

#define MFMA16(a, b, c) __builtin_amdgcn_mfma_f32_16x16x32_bf16((a), (b), (c), 0, 0, 0)

// async global->LDS, 16B per lane; LDS dest = wave-uniform base + lane*16
__device__ __forceinline__ void gll16(const void* g, void* l) {
    __builtin_amdgcn_global_load_lds(
        (const __attribute__((address_space(1))) unsigned int*)g,
        (__attribute__((address_space(3))) unsigned int*)l, 16, 0, 0);
}

__device__ __forceinline__ u16 f2b(float f) {   // f32 -> bf16 RNE (scalar)
    unsigned int u = __float_as_uint(f);
    u += 0x7fffu + ((u >> 16) & 1u);
    return (u16)(u >> 16);
}

__device__ __forceinline__ unsigned int pkbf(float a, float b) {  // packed bf16x2
    return (unsigned int)f2b(a) | ((unsigned int)f2b(b) << 16);
}

// ---------------------------------------------------------------- one cast kernel
// blocks 0..2047: x (4M f32). blocks 2048..4095: the four 1M-element weights.
__global__ __launch_bounds__(256) void cast_all(const float* __restrict__ x,
                                                const float* __restrict__ w0,
                                                const float* __restrict__ w1,
                                                const float* __restrict__ w2,
                                                const float* __restrict__ w3,
                                                u16* __restrict__ xb,
                                                u16* __restrict__ wb) {
    const int bid = blockIdx.x;
    const float* s; u16* d; int off;
    if (bid < 2048) { s = x; d = xb; off = bid; }
    else {
        const int wi = (bid - 2048) >> 9;
        s = (wi == 0) ? w0 : (wi == 1) ? w1 : (wi == 2) ? w2 : w3;
        d = wb + (size_t)wi * 1048576;
        off = (bid - 2048) & 511;
    }
    const int i = (off * 256 + threadIdx.x) * 8;
    float4 a = *(const float4*)(s + i);
    float4 b = *(const float4*)(s + i + 4);
    *(uint4*)(d + i) = make_uint4(pkbf(a.x, a.y), pkbf(a.z, a.w),
                                  pkbf(b.x, b.y), pkbf(b.z, b.w));
}

// ---------------------------------------------------------------- GEMM, dbuf K-loop
// Y = A[M,K] @ W[rows,K]^T, bf16 in, fp32 acc, BMxBN tile, BK=32, 4 waves (2x2),
// LDS double-buffered, SLOTS K-tiles staged/computed per barrier (more compute
// per vmcnt(0) drain — the only lever under gll16+syncthreads semantics).
// MODE 0: f32 out, stride ldY. MODE 1 (BM=BN=128): fused QKV epilogue — cols<2048
// -> bf16 qk (stride 2048); cols>=2048 (V proj) -> transposed into vT.
template <int BM, int BN, int MODE, int SLOTS>
__global__ __launch_bounds__(256) void gemm_bt(const u16* __restrict__ A,
                                               const u16* __restrict__ W,
                                               void* __restrict__ Yv,
                                               u16* __restrict__ vT,
                                               int K, int ldY) {
    constexpr int MI = BM / 32, NJ = BN / 32;      // frags per wave
    constexpr int ACH = BM / 16;                   // A staging chunks (1KB each)
    constexpr int NPW = (BM + BN) / 64;            // chunks per wave per slot
    __shared__ u16 As[2][SLOTS][BM * 32];
    __shared__ u16 Bs[2][SLOTS][BN * 32];
    const int t = threadIdx.x, w = t >> 6, lane = t & 63;
    const int quad = lane >> 4, m16 = lane & 15;
    const int wr = (w >> 1) * (BM / 2), wc = (w & 1) * (BN / 2);
    const int row0 = blockIdx.x * BM, col0 = blockIdx.y * BN;
    const int srow = lane >> 2, scol = (lane & 3) * 8;

    auto stage = [&](int buf, int slot, int k0) {
#pragma unroll
        for (int cc = 0; cc < NPW; ++cc) {
            const int c = w * NPW + cc;
            if (c < ACH)
                gll16(A + (size_t)(row0 + c * 16 + srow) * K + k0 + scol,
                      &As[buf][slot][c * 512]);
            else
                gll16(W + (size_t)(col0 + (c - ACH) * 16 + srow) * K + k0 + scol,
                      &Bs[buf][slot][(c - ACH) * 512]);
        }
    };

    f32x4 acc[MI][NJ];
#pragma unroll
    for (int i = 0; i < MI; ++i)
#pragma unroll
        for (int j = 0; j < NJ; ++j) acc[i][j] = (f32x4){0.f, 0.f, 0.f, 0.f};

    auto compute_tile = [&](int buf, int slot) {
        bf16x8 af[MI], bf[NJ];
#pragma unroll
        for (int i = 0; i < MI; ++i)
            af[i] = *(const bf16x8*)&As[buf][slot][(wr + i * 16 + m16) * 32 + quad * 8];
#pragma unroll
        for (int j = 0; j < NJ; ++j)
            bf[j] = *(const bf16x8*)&Bs[buf][slot][(wc + j * 16 + m16) * 32 + quad * 8];
#pragma unroll
        for (int i = 0; i < MI; ++i)
#pragma unroll
            for (int j = 0; j < NJ; ++j) acc[i][j] = MFMA16(af[i], bf[j], acc[i][j]);
    };

#pragma unroll
    for (int s = 0; s < SLOTS; ++s) stage(0, s, s * 32);
    const int ngroups = K / (32 * SLOTS);
    for (int g = 0; g < ngroups; ++g) {
        const int buf = g & 1;
        __syncthreads();                       // group g landed; buf^1 free
        const int kn = (g + 1) * SLOTS * 32;   // prefetch group g+1
        if (kn < K) {
#pragma unroll
            for (int s = 0; s < SLOTS; ++s) stage(buf ^ 1, s, kn + s * 32);
        }
#pragma unroll
        for (int s = 0; s < SLOTS; ++s) compute_tile(buf, s);
    }
    // epilogue: D[row=quad*4+r][col=m16] per 16x16 tile
    if constexpr (MODE == 0) {
#pragma unroll
        for (int i = 0; i < MI; ++i)
#pragma unroll
            for (int j = 0; j < NJ; ++j)
#pragma unroll
                for (int r = 0; r < 4; ++r)
                    ((float*)Yv)[(size_t)(row0 + wr + i * 16 + quad * 4 + r) * ldY +
                                 col0 + wc + j * 16 + m16] = acc[i][j][r];
    } else {
        if (col0 < 2048) {              // Q/K projection -> bf16, stride 2048
            u16* qk = (u16*)Yv;
#pragma unroll
            for (int i = 0; i < MI; ++i)
#pragma unroll
                for (int j = 0; j < NJ; ++j)
#pragma unroll
                    for (int r = 0; r < 4; ++r)
                        qk[(size_t)(row0 + wr + i * 16 + quad * 4 + r) * 2048 +
                           col0 + wc + j * 16 + m16] = f2b(acc[i][j][r]);
        } else {                        // V projection -> transposed vT
#pragma unroll
            for (int i = 0; i < MI; ++i) {
                const int rbase = row0 + wr + i * 16;
                const int bb = rbase >> 10;
                const int tok0 = (rbase & 1023) + quad * 4;
#pragma unroll
                for (int j = 0; j < NJ; ++j) {
                    const int vTrow = bb * 1024 + (col0 + wc + j * 16 + m16 - 2048);
                    *(uint2*)(vT + (size_t)vTrow * 1024 + tok0) =
                        make_uint2(pkbf(acc[i][j][0], acc[i][j][1]),
                                   pkbf(acc[i][j][2], acc[i][j][3]));
                }
            }
        }
    }
}

// ---------------------------------------------------------------- based attention
// Triangular pairing (tA=p, tB=15-p: 17 units/block, uniform). LDS-staged k/v
// (coalesced gll16 — R10 showed per-lane global frag loads regress), Q in
// registers. TWO kt-tiles per barrier: stage 32 KB/group, double-buffered, one
// __syncthreads per group -> half the barriers, 2x compute per drain.
// A/B units computed jointly sharing k/v frags; separate wave-private Ss.
__global__ __launch_bounds__(256) void based_attn(const u16* __restrict__ qkm,
                                                  const u16* __restrict__ vT,
                                                  u16* __restrict__ o) {
    __shared__ u16 ks[2][2][2][64][32];  // [buf][slot][dblk][key][32]
    __shared__ u16 vs[2][2][2][64][32];  // [buf][slot][kb][vdim][32 keys]
    __shared__ u16 SsA[2][64][32];       // [kb][qrow][32 keys] (wave-private rows)
    __shared__ u16 SsB[2][64][32];

    const int t = threadIdx.x, w = t >> 6, lane = t & 63;
    const int quad = lane >> 4, m16 = lane & 15;
    const int p = blockIdx.x, h = blockIdx.y, b = blockIdx.z;
    const int tA = p, tB = 15 - p;
    const int srow = lane >> 2, s8 = (lane & 3) * 8;
    const int qrow = w * 16 + m16;       // this lane's q-row (local to tile)

    const size_t qbase = (size_t)b * 1024 * 2048 + h * 64;   // + row*2048
    const size_t kbase = qbase + 1024;
    const size_t vbase = ((size_t)b * 1024 + h * 64) * 1024; // + vd*1024 + tok

    // Q frags in registers (4 scattered 16B loads, once — outside the loop)
    bf16x8 qfA[2], qfB[2];
#pragma unroll
    for (int kd = 0; kd < 2; ++kd) {
        qfA[kd] = *(const bf16x8*)(qkm + qbase +
                   (size_t)(tA * 64 + qrow) * 2048 + kd * 32 + quad * 8);
        qfB[kd] = *(const bf16x8*)(qkm + qbase +
                   (size_t)(tB * 64 + qrow) * 2048 + kd * 32 + quad * 8);
    }

    // stage one kt-tile into [buf][slot]; wave w takes chunks 2w, 2w+1 (k and v)
    auto stage_tile = [&](int kt, int buf, int slot) {
#pragma unroll
        for (int cc = 0; cc < 2; ++cc) {
            const int c = w * 2 + cc;
            const int blk = c >> 2, rc = c & 3;
            gll16(qkm + kbase + (size_t)(kt * 64 + rc * 16 + srow) * 2048 + blk * 32 + s8,
                  &ks[buf][slot][blk][rc * 16][0]);
            gll16(vT + vbase + (size_t)(rc * 16 + srow) * 1024 + kt * 64 + blk * 32 + s8,
                  &vs[buf][slot][blk][rc * 16][0]);
        }
    };

    bf16x8 ones;
#pragma unroll
    for (int e = 0; e < 8; ++e) ones[e] = (short)0x3F80;

    f32x4 numA[4], numB[4], denA, denB;
    denA = denB = (f32x4){0.f, 0.f, 0.f, 0.f};
#pragma unroll
    for (int j = 0; j < 4; ++j) numA[j] = numB[j] = (f32x4){0.f, 0.f, 0.f, 0.f};

    auto compute = [&](int buf, int slot, int kt) {
        const bool doA = (kt <= tA);
        // Phase 1: S^T = K * Q^T (shared K-frags for both units)
        f32x4 sA[4], sB[4];
#pragma unroll
        for (int jk = 0; jk < 4; ++jk)
            sA[jk] = sB[jk] = (f32x4){0.f, 0.f, 0.f, 0.f};
#pragma unroll
        for (int kd = 0; kd < 2; ++kd)
#pragma unroll
            for (int jk = 0; jk < 4; ++jk) {
                bf16x8 af = *(const bf16x8*)&ks[buf][slot][kd][jk * 16 + m16][quad * 8];
                sB[jk] = MFMA16(af, qfB[kd], sB[jk]);
                if (doA) sA[jk] = MFMA16(af, qfA[kd], sA[jk]);
            }
        // transform: sc = 0.5*(s+1)^2 + 0.5, s = dot/8; mask on diagonal tiles
#pragma unroll
        for (int jk = 0; jk < 4; ++jk) {
            const int kl = jk * 16 + quad * 4;
            float scB[4];
#pragma unroll
            for (int r = 0; r < 4; ++r) {
                const float u = fmaf(sB[jk][r], 0.125f, 1.0f);
                scB[r] = fmaf(u * 0.5f, u, 0.5f);
            }
            if (kt == tB) {
#pragma unroll
                for (int r = 0; r < 4; ++r)
                    if (kl + r > qrow) scB[r] = 0.f;
            }
            *(uint2*)&SsB[kl >> 5][qrow][kl & 31] =
                make_uint2(pkbf(scB[0], scB[1]), pkbf(scB[2], scB[3]));
            if (doA) {
                float scA[4];
#pragma unroll
                for (int r = 0; r < 4; ++r) {
                    const float u = fmaf(sA[jk][r], 0.125f, 1.0f);
                    scA[r] = fmaf(u * 0.5f, u, 0.5f);
                }
                if (kt == tA) {
#pragma unroll
                    for (int r = 0; r < 4; ++r)
                        if (kl + r > qrow) scA[r] = 0.f;
                }
                *(uint2*)&SsA[kl >> 5][qrow][kl & 31] =
                    make_uint2(pkbf(scA[0], scA[1]), pkbf(scA[2], scA[3]));
            }
        }
        // Phase 2: num += S*V, den += S*ones (shared V-frags); same-wave LDS
        // round-trip ordered by lgkmcnt — no barrier needed.
#pragma unroll
        for (int kb = 0; kb < 2; ++kb) {
            bf16x8 vf[4];
#pragma unroll
            for (int j = 0; j < 4; ++j)
                vf[j] = *(const bf16x8*)&vs[buf][slot][kb][j * 16 + m16][quad * 8];
            bf16x8 sfB = *(const bf16x8*)&SsB[kb][qrow][quad * 8];
#pragma unroll
            for (int j = 0; j < 4; ++j) numB[j] = MFMA16(sfB, vf[j], numB[j]);
            denB = MFMA16(sfB, ones, denB);
            if (doA) {
                bf16x8 sfA = *(const bf16x8*)&SsA[kb][qrow][quad * 8];
#pragma unroll
                for (int j = 0; j < 4; ++j) numA[j] = MFMA16(sfA, vf[j], numA[j]);
                denA = MFMA16(sfA, ones, denA);
            }
        }
    };

    // prologue: group 0 = tiles 0,1 (tB >= 8, so tile 1 always exists)
    stage_tile(0, 0, 0);
    stage_tile(1, 0, 1);

    const int ngroups = (tB + 2) >> 1;   // tiles 0..tB in groups of 2
    for (int g = 0; g < ngroups; ++g) {
        const int buf = g & 1;
        __syncthreads();                 // group g landed; buf^1 free to refill
        const int kn = (g + 1) * 2;      // prefetch group g+1 (hidden by compute)
        if (kn <= tB) {
            stage_tile(kn, buf ^ 1, 0);
            if (kn + 1 <= tB) stage_tile(kn + 1, buf ^ 1, 1);
        }
        const int kt0 = g * 2;
        compute(buf, 0, kt0);
        if (kt0 + 1 <= tB) compute(buf, 1, kt0 + 1);
    }

    // epilogue: o[token][h*64+vdim] = num/den (bf16)
#pragma unroll
    for (int r = 0; r < 4; ++r) {
        const float invA = 1.0f / denA[r], invB = 1.0f / denB[r];
        const int rowoff = w * 16 + quad * 4 + r;
        const size_t tokA = (size_t)(b * 1024 + tA * 64 + rowoff);
        const size_t tokB = (size_t)(b * 1024 + tB * 64 + rowoff);
#pragma unroll
        for (int j = 0; j < 4; ++j) {
            o[tokA * 1024 + h * 64 + j * 16 + m16] = f2b(numA[j][r] * invA);
            o[tokB * 1024 + h * 64 + j * 16 + m16] = f2b(numB[j][r] * invB);
        }
    }
}

// ---------------------------------------------------------------- launch
extern "C" void kernel_launch(void* const* d_in, const int* in_sizes, int n_in,
                              void* d_out, int out_size, void* d_ws, size_t ws_size,
                              hipStream_t stream) {
    const float* x  = (const float*)d_in[0];
    const float* Wq = (const float*)d_in[1];
    const float* Wk = (const float*)d_in[2];
    const float* Wv = (const float*)d_in[3];
    const float* Wo = (const float*)d_in[4];
    float* out = (float*)d_out;

    const size_t MEL = 4096ull * 1024ull;        // 4M elements
    u16* xb   = (u16*)d_ws;                      // 4096 x 1024
    u16* Wqkv = xb + MEL;                        // 3072 x 1024 (Wq|Wk|Wv rows)
    u16* Wob  = Wqkv + 3ull * 1024 * 1024;       // 1024 x 1024 (contiguous after)
    u16* qk   = Wob + 1024ull * 1024;            // 4096 x 2048 (q|k)
    u16* vT   = qk + 2ull * MEL;                 // [b*1024+h*64+vd][1024 tokens]
    u16* o    = vT + MEL;                        // 4096 x 1024

    cast_all<<<4096, 256, 0, stream>>>(x, Wq, Wk, Wv, Wo, xb, Wqkv);

    dim3 gq(32, 24);   // 4096/128 x 3072/128; y>=16 blocks write vT directly
    gemm_bt<128, 128, 1, 1><<<gq, 256, 0, stream>>>(xb, Wqkv, qk, vT, 1024, 2048);

    dim3 ga(8, 16, 4); // pair index x heads x batch — uniform work per block
    based_attn<<<ga, 256, 0, stream>>>(qk, vT, o);

    // 64x64 tiles, 1024 blocks (4/CU), 2 K-tiles per barrier (32KB LDS, no
    // occupancy loss) — halves barrier-drain count on the latency-bound o-GEMM
    dim3 go(64, 16);
    gemm_bt<64, 64, 0, 2><<<go, 256, 0, stream>>>(o, Wob, (void*)out, nullptr, 1024, 1024);
}